// Round 3
// baseline (1621.530 us; speedup 1.0000x reference)
//
#include <hip/hip_runtime.h>
#include <hip/hip_bf16.h>

typedef __attribute__((ext_vector_type(8))) short s8b;     // 8 bf16 (4 VGPRs)
typedef __attribute__((ext_vector_type(4))) float f32x4;   // MFMA accumulator

#define NND 50000
#define NED 800000

// workspace layout (bf16-element offsets for weights, byte offsets for f32)
#define WM1T_OFF 0         // [128][384] folded+transposed Wm1'
#define WM2T_OFF 49152     // [128][128]
#define WV1T_OFF 65536     // [128][128]
#define WV2T_OFF 81920     // [80][128]
#define WS1T_OFF 92160     // [128][256]
#define WS2T_OFF 124928    // [128][128]
#define BM1F_BYTE 282624   // 128 f32 (folded bias)
#define ACC_BYTE  283136   // f32 accumulators start (16B aligned)
#define ZACC_ELEMS (NND*48)
#define MACC_ELEMS (NND*128)
#define ACC_TOTAL (ZACC_ELEMS + MACC_ELEMS + NND)
#define WS_NEED (ACC_BYTE + (size_t)ACC_TOTAL*4)

__device__ __forceinline__ short f2bs(float x){
    __hip_bfloat16 b = __float2bfloat16(x);
    return __builtin_bit_cast(short, b);
}
__device__ __forceinline__ float silu_f(float x){ return x / (1.0f + __expf(-x)); }

// load 8 consecutive f32 (16B-aligned) -> bf16 A/B fragment
__device__ __forceinline__ s8b load8f_bf(const float* p){
    f32x4 a = *(const f32x4*)p;
    f32x4 b = *(const f32x4*)(p + 4);
    s8b r;
    r[0]=f2bs(a[0]); r[1]=f2bs(a[1]); r[2]=f2bs(a[2]); r[3]=f2bs(a[3]);
    r[4]=f2bs(b[0]); r[5]=f2bs(b[1]); r[6]=f2bs(b[2]); r[7]=f2bs(b[3]);
    return r;
}

#define MFMA16(a,b,c) __builtin_amdgcn_mfma_f32_16x16x32_bf16((a),(b),(c),0,0,0)

// ---------------- zero accumulators (no SDMA memset) ----------------
__global__ __launch_bounds__(256) void zero_kernel(float* __restrict__ p, int n)
{
    int i = blockIdx.x*256 + threadIdx.x;
    int stride = gridDim.x*256;
    for (; i < n; i += stride) p[i] = 0.0f;
}

// ---------------- weight prep ----------------
__global__ __launch_bounds__(256) void fold_kernel(
    const float* __restrict__ We, const float* __restrict__ be,
    const float* __restrict__ Wm1, const float* __restrict__ bm1,
    short* __restrict__ Wm1T, float* __restrict__ bm1f)
{
    int idx = blockIdx.x*256 + threadIdx.x;
    if (idx >= 128*384) return;
    int n = idx / 384, k = idx - n*384;
    float v;
    if (k < 356) v = Wm1[(size_t)k*128 + n];
    else if (k < 372) {
        int j = k - 356; float s = 0.f;
        for (int c = 0; c < 128; c++)
            s += We[j*128 + c] * Wm1[(size_t)(356+c)*128 + n];
        v = s;
    } else v = 0.f;
    Wm1T[(size_t)n*384 + k] = f2bs(v);
    if (k == 0) {
        float s = bm1[n];
        for (int c = 0; c < 128; c++)
            s += be[c] * Wm1[(size_t)(356+c)*128 + n];
        bm1f[n] = s;
    }
}

__global__ __launch_bounds__(256) void prep_kernel(
    const float* __restrict__ Wm2, const float* __restrict__ Wv1,
    const float* __restrict__ Wv2, const float* __restrict__ Ws1,
    const float* __restrict__ Ws2, short* __restrict__ wsb)
{
    int i = blockIdx.x*256 + threadIdx.x;
    if (i < 16384) { int k=i>>7, n=i&127; wsb[WM2T_OFF + n*128 + k] = f2bs(Wm2[i]); return; }
    i -= 16384;
    if (i < 16384) { int k=i>>7, n=i&127; wsb[WV1T_OFF + n*128 + k] = f2bs(Wv1[i]); return; }
    i -= 16384;
    if (i < 10240) { int k=i/80, n=i-k*80; wsb[WV2T_OFF + n*128 + k] = f2bs(Wv2[i]); return; }
    i -= 10240;
    if (i < 32768) { int k=i>>7, n=i&127; wsb[WS1T_OFF + n*256 + k] = f2bs(Ws1[i]); return; }
    i -= 32768;
    if (i < 16384) { int k=i>>7, n=i&127; wsb[WS2T_OFF + n*128 + k] = f2bs(Ws2[i]); return; }
}

// ---------------- edge kernel ----------------
// 64 edges/block, 4 waves, each wave owns 16 edges; __syncthreads between phases.
__global__ __launch_bounds__(256) void edge_kernel(
    const float* __restrict__ Z, const float* __restrict__ h,
    const int* __restrict__ ei,
    const float* __restrict__ edf, const float* __restrict__ edv,
    const short* __restrict__ Wm1T, const float* __restrict__ bm1f,
    const short* __restrict__ Wm2T, const float* __restrict__ bm2,
    const short* __restrict__ Wv1T, const float* __restrict__ bv1,
    const short* __restrict__ Wv2T, const float* __restrict__ bv2,
    float* __restrict__ Zacc, float* __restrict__ macc, float* __restrict__ cnt)
{
    __shared__ float zsh[64*64];                  // Z_ij f32: [e][d*20+t*4+h]
    __shared__ __align__(16) short ssh[64*136];   // stage: invar/edf -> act1 -> msg -> act3
    __shared__ int srcs[64], dsts[64];

    const int tid  = threadIdx.x;
    const int lane = tid & 63;
    const int wave = tid >> 6;
    const int mb   = wave * 16;
    const int ebase= blockIdx.x * 64;

    // ---- Phase A1: indices + Z_ij into LDS ----
    if (lane < 16) {
        int e = ebase + mb + lane;
        int s = ei[e], d = ei[NED + e];
        srcs[mb + lane] = s; dsts[mb + lane] = d;
        atomicAdd(cnt + d, 1.0f);
    }
    const int rowA = mb + (lane >> 2);
    const int subA = lane & 3;
    {
        const int e   = ebase + rowA;
        const int s = ei[e], d = ei[NED + e];
        const float* Zs = Z + (size_t)s*48;
        const float* Zd = Z + (size_t)d*48;
        #pragma unroll
        for (int ii = 0; ii < 12; ii++) {
            int i = subA + ii*4;                   // 0..47 = d*16 + t*4 + h
            int dd = i >> 4;
            zsh[rowA*64 + dd*20 + (i & 15)] = Zd[i] - Zs[i];
        }
        if (subA < 3) {
            float ev = edv[(size_t)e*3 + subA];
            #pragma unroll
            for (int hh = 0; hh < 4; hh++) zsh[rowA*64 + subA*20 + 16 + hh] = ev;
        }
    }
    __syncthreads();

    // ---- Phase A2: invariants + edf stage ----
    {
        const int e = ebase + rowA;
        float iv[25]; float ssq = 0.f;
        #pragma unroll
        for (int ii = 0; ii < 25; ii++) {
            int idx = subA*25 + ii;                // 0..99 = t*20 + r*4 + h
            int hh = idx & 3, rr = (idx >> 2) % 5, tt = idx / 20;
            float a0 = 0.f;
            #pragma unroll
            for (int dd = 0; dd < 3; dd++)
                a0 += zsh[rowA*64 + dd*20 + tt*4 + hh] * zsh[rowA*64 + dd*20 + rr*4 + hh];
            iv[ii] = a0; ssq += a0*a0;
        }
        ssq += __shfl_xor(ssq, 1);
        ssq += __shfl_xor(ssq, 2);
        const float rn = 1.0f / fmaxf(sqrtf(ssq), 1e-12f);
        #pragma unroll
        for (int ii = 0; ii < 25; ii++)
            ssh[rowA*136 + subA*25 + ii] = f2bs(iv[ii]*rn);
        #pragma unroll
        for (int j = subA; j < 16; j += 4)
            ssh[rowA*136 + 100 + j] = f2bs(edf[(size_t)e*16 + j]);
        #pragma unroll
        for (int j = subA; j < 20; j += 4)
            ssh[rowA*136 + 116 + j] = 0;
    }
    __syncthreads();

    // ---- GEMM phase: wave's 16x128 tile, MFMA 16x16x32 ----
    const int quad = lane >> 4;
    const int c15  = lane & 15;
    const int rA   = mb + c15;                // A-fragment row
    const int dn   = dsts[rA];
    const int sn   = srcs[rA];
    const float* hd = h + (size_t)dn*128 + quad*8;
    const float* hs = h + (size_t)sn*128 + quad*8;
    const short* sA = ssh + rA*136 + quad*8;
    const f32x4 z4 = {0.f,0.f,0.f,0.f};

    // Layer 1: x'[384] @ Wm1T' -> 128, K = [h_i | h_j | invar+edf+pad]
    f32x4 acc1[8];
    #pragma unroll
    for (int nt = 0; nt < 8; nt++) acc1[nt] = z4;
    {
        const short* Bp = Wm1T + (size_t)c15*384 + quad*8;
        #pragma unroll
        for (int ks = 0; ks < 12; ks++) {
            s8b a;
            if (ks < 4)      a = load8f_bf(hd + ks*32);
            else if (ks < 8) a = load8f_bf(hs + (ks-4)*32);
            else             a = *(const s8b*)(sA + (ks-8)*32);
            #pragma unroll
            for (int nt = 0; nt < 8; nt++) {
                s8b b = *(const s8b*)(Bp + nt*(16*384) + ks*32);
                acc1[nt] = MFMA16(a, b, acc1[nt]);
            }
        }
    }
    __syncthreads();
    #pragma unroll
    for (int nt = 0; nt < 8; nt++) {
        const int col = nt*16 + c15;
        const float bias = bm1f[col];
        #pragma unroll
        for (int r = 0; r < 4; r++)
            ssh[(mb + quad*4 + r)*136 + col] = f2bs(silu_f(acc1[nt][r] + bias));
    }
    __syncthreads();

    // Layer 2: act1 @ Wm2 -> msg ; atomic-add msg (f32) to macc
    f32x4 acc2[8];
    #pragma unroll
    for (int nt = 0; nt < 8; nt++) acc2[nt] = z4;
    {
        const short* Bp = Wm2T + (size_t)c15*128 + quad*8;
        #pragma unroll
        for (int ks = 0; ks < 4; ks++) {
            s8b a = *(const s8b*)(sA + ks*32);
            #pragma unroll
            for (int nt = 0; nt < 8; nt++) {
                s8b b = *(const s8b*)(Bp + nt*(16*128) + ks*32);
                acc2[nt] = MFMA16(a, b, acc2[nt]);
            }
        }
    }
    __syncthreads();
    #pragma unroll
    for (int nt = 0; nt < 8; nt++) {
        const int col = nt*16 + c15;
        const float bias = bm2[col];
        #pragma unroll
        for (int r = 0; r < 4; r++) {
            const int rw = mb + quad*4 + r;
            float v = silu_f(acc2[nt][r] + bias);
            atomicAdd(macc + (size_t)dsts[rw]*128 + col, v);
            ssh[rw*136 + col] = f2bs(v);
        }
    }
    __syncthreads();

    // Layer 3: msg @ Wv1 -> act3
    f32x4 acc3[8];
    #pragma unroll
    for (int nt = 0; nt < 8; nt++) acc3[nt] = z4;
    {
        const short* Bp = Wv1T + (size_t)c15*128 + quad*8;
        #pragma unroll
        for (int ks = 0; ks < 4; ks++) {
            s8b a = *(const s8b*)(sA + ks*32);
            #pragma unroll
            for (int nt = 0; nt < 8; nt++) {
                s8b b = *(const s8b*)(Bp + nt*(16*128) + ks*32);
                acc3[nt] = MFMA16(a, b, acc3[nt]);
            }
        }
    }
    __syncthreads();
    #pragma unroll
    for (int nt = 0; nt < 8; nt++) {
        const int col = nt*16 + c15;
        const float bias = bv1[col];
        #pragma unroll
        for (int r = 0; r < 4; r++)
            ssh[(mb + quad*4 + r)*136 + col] = f2bs(silu_f(acc3[nt][r] + bias));
    }
    __syncthreads();

    // Layer 4: act3 @ Wv2 -> basis[80] ; contract with Z_ij ; atomic to Zacc
    f32x4 acc4[5];
    #pragma unroll
    for (int nt = 0; nt < 5; nt++) acc4[nt] = z4;
    {
        const short* Bp = Wv2T + (size_t)c15*128 + quad*8;
        #pragma unroll
        for (int ks = 0; ks < 4; ks++) {
            s8b a = *(const s8b*)(sA + ks*32);
            #pragma unroll
            for (int nt = 0; nt < 5; nt++) {
                s8b b = *(const s8b*)(Bp + nt*(16*128) + ks*32);
                acc4[nt] = MFMA16(a, b, acc4[nt]);
            }
        }
    }
    {
        const int hh = c15 & 3;                   // basis col = t*16 + (k*4+h); c15 = k*4+h
        float bs[5];
        #pragma unroll
        for (int t = 0; t < 5; t++) bs[t] = bv2[t*16 + c15];
        #pragma unroll
        for (int r = 0; r < 4; r++) {
            const int rw = mb + quad*4 + r;
            const int eg = dsts[rw];
            float bt[5];
            #pragma unroll
            for (int t = 0; t < 5; t++) bt[t] = acc4[t][r] + bs[t];
            #pragma unroll
            for (int dd = 0; dd < 3; dd++) {
                float s0 = 0.f;
                #pragma unroll
                for (int t = 0; t < 5; t++)
                    s0 += zsh[rw*64 + dd*20 + t*4 + hh] * bt[t];
                atomicAdd(Zacc + (size_t)eg*48 + dd*16 + c15, s0);
            }
        }
    }
}

// ---------------- node kernel ----------------
__global__ __launch_bounds__(256) void node_kernel(
    const float* __restrict__ h,
    const short* __restrict__ Ws1T, const float* __restrict__ bs1,
    const short* __restrict__ Ws2T, const float* __restrict__ bs2,
    const float* __restrict__ Zacc, const float* __restrict__ macc,
    const float* __restrict__ cnt, float* __restrict__ out)
{
    __shared__ __align__(16) short ssh[64*136];   // m stage -> act1
    const int tid = threadIdx.x, lane = tid & 63, wave = tid >> 6;
    const int mb = wave*16;
    const int nbase = blockIdx.x * 64;

    // Z_out = Zacc / max(cnt,1)
    for (int i = tid; i < 64*48; i += 256) {
        int nl = i / 48, c2 = i - nl*48;
        int nd = nbase + nl;
        if (nd < NND) {
            float ct = fmaxf(cnt[nd], 1.0f);
            out[(size_t)nd*48 + c2] = Zacc[(size_t)nd*48 + c2] / ct;
        }
    }

    // stage m (bf16)
    {
        const int row = mb + (lane >> 2);
        const int sub = lane & 3;
        int nd = nbase + row; if (nd >= NND) nd = 0;
        const float* mr = macc + (size_t)nd*128 + sub*32;
        #pragma unroll
        for (int j = 0; j < 8; j++) {
            f32x4 v = *(const f32x4*)(mr + j*4);
            int cb = row*136 + sub*32 + j*4;
            ssh[cb+0] = f2bs(v[0]); ssh[cb+1] = f2bs(v[1]);
            ssh[cb+2] = f2bs(v[2]); ssh[cb+3] = f2bs(v[3]);
        }
    }
    __syncthreads();

    const int quad = lane >> 4, c15 = lane & 15;
    const int rA = mb + c15;
    int ndA = nbase + rA; if (ndA >= NND) ndA = 0;   // clamp; stores guarded
    const float* hA = h + (size_t)ndA*128 + quad*8;
    const short* sA = ssh + rA*136 + quad*8;
    const f32x4 z4 = {0.f,0.f,0.f,0.f};

    // GEMM1: [h | m] (K=256) @ Ws1
    f32x4 acc1[8];
    #pragma unroll
    for (int nt = 0; nt < 8; nt++) acc1[nt] = z4;
    {
        const short* Bp = Ws1T + (size_t)c15*256 + quad*8;
        #pragma unroll
        for (int ks = 0; ks < 8; ks++) {
            s8b a;
            if (ks < 4) a = load8f_bf(hA + ks*32);
            else        a = *(const s8b*)(sA + (ks-4)*32);
            #pragma unroll
            for (int nt = 0; nt < 8; nt++) {
                s8b b = *(const s8b*)(Bp + nt*(16*256) + ks*32);
                acc1[nt] = MFMA16(a, b, acc1[nt]);
            }
        }
    }
    __syncthreads();
    #pragma unroll
    for (int nt = 0; nt < 8; nt++) {
        const int col = nt*16 + c15;
        const float bias = bs1[col];
        #pragma unroll
        for (int r = 0; r < 4; r++)
            ssh[(mb + quad*4 + r)*136 + col] = f2bs(silu_f(acc1[nt][r] + bias));
    }
    __syncthreads();

    // GEMM2: act @ Ws2 -> h_out
    f32x4 acc2[8];
    #pragma unroll
    for (int nt = 0; nt < 8; nt++) acc2[nt] = z4;
    {
        const short* Bp = Ws2T + (size_t)c15*128 + quad*8;
        #pragma unroll
        for (int ks = 0; ks < 4; ks++) {
            s8b a = *(const s8b*)(sA + ks*32);
            #pragma unroll
            for (int nt = 0; nt < 8; nt++) {
                s8b b = *(const s8b*)(Bp + nt*(16*128) + ks*32);
                acc2[nt] = MFMA16(a, b, acc2[nt]);
            }
        }
    }
    {
        float* oh = out + (size_t)NND*48;
        #pragma unroll
        for (int nt = 0; nt < 8; nt++) {
            const int col = nt*16 + c15;
            const float bias = bs2[col];
            #pragma unroll
            for (int r = 0; r < 4; r++) {
                const int rw = mb + quad*4 + r;
                const int nd = nbase + rw;
                if (nd < NND)
                    oh[(size_t)nd*128 + col] = acc2[nt][r] + bias;
            }
        }
    }
}

extern "C" void kernel_launch(void* const* d_in, const int* in_sizes, int n_in,
                              void* d_out, int out_size, void* d_ws, size_t ws_size,
                              hipStream_t stream)
{
    const float* Z   = (const float*)d_in[0];
    const float* h   = (const float*)d_in[1];
    const int*   ei  = (const int*)d_in[2];
    const float* edf = (const float*)d_in[3];
    const float* edv = (const float*)d_in[4];
    // d_in[5] = edge_distance (unused by reference)
    const float* We  = (const float*)d_in[6];
    const float* be  = (const float*)d_in[7];
    const float* Wm1 = (const float*)d_in[8];
    const float* bm1 = (const float*)d_in[9];
    const float* Wm2 = (const float*)d_in[10];
    const float* bm2 = (const float*)d_in[11];
    const float* Wv1 = (const float*)d_in[12];
    const float* bv1 = (const float*)d_in[13];
    const float* Wv2 = (const float*)d_in[14];
    const float* bv2 = (const float*)d_in[15];
    const float* Ws1 = (const float*)d_in[16];
    const float* bs1 = (const float*)d_in[17];
    const float* Ws2 = (const float*)d_in[18];
    const float* bs2 = (const float*)d_in[19];

    if (ws_size < WS_NEED) return;

    char* wsc = (char*)d_ws;
    short* wsb = (short*)d_ws;
    float* bm1f = (float*)(wsc + BM1F_BYTE);
    float* Zacc = (float*)(wsc + ACC_BYTE);
    float* macc = Zacc + ZACC_ELEMS;
    float* cnt  = macc + MACC_ELEMS;

    zero_kernel<<<2048, 256, 0, stream>>>(Zacc, ACC_TOTAL);
    fold_kernel<<<192, 256, 0, stream>>>(We, be, Wm1, bm1, wsb + WM1T_OFF, bm1f);
    prep_kernel<<<360, 256, 0, stream>>>(Wm2, Wv1, Wv2, Ws1, Ws2, wsb);
    edge_kernel<<<NED/64, 256, 0, stream>>>(Z, h, ei, edf, edv,
        wsb + WM1T_OFF, bm1f, wsb + WM2T_OFF, bm2, wsb + WV1T_OFF, bv1,
        wsb + WV2T_OFF, bv2, Zacc, macc, cnt);
    node_kernel<<<(NND + 63)/64, 256, 0, stream>>>(h, wsb + WS1T_OFF, bs1,
        wsb + WS2T_OFF, bs2, Zacc, macc, cnt, (float*)d_out);
}

// Round 4
// 1197.003 us; speedup vs baseline: 1.3547x; 1.3547x over previous
//
#include <hip/hip_runtime.h>
#include <hip/hip_bf16.h>

typedef __attribute__((ext_vector_type(8))) short s8b;     // 8 bf16 (4 VGPRs)
typedef __attribute__((ext_vector_type(4))) float f32x4;   // MFMA accumulator

#define NND 50000
#define NED 800000
#define EPB 128     // edges per block
#define EPW 32      // edges per wave
#define ZR  66      // zsh row stride in shorts (bank-spread)

// workspace layout (bf16-element offsets for weights, byte offsets for f32)
#define WM1T_OFF 0         // [128][384] folded+transposed Wm1'
#define WM2T_OFF 49152     // [128][128]
#define WV1T_OFF 65536     // [128][128]
#define WV2T_OFF 81920     // [80][128]
#define WS1T_OFF 92160     // [128][256]
#define WS2T_OFF 124928    // [128][128]
#define BM1F_BYTE 282624   // 128 f32 (folded bias)
#define ACC_BYTE  283136   // f32 accumulators start (16B aligned)
#define ZACC_ELEMS (NND*48)
#define MACC_ELEMS (NND*128)
#define ACC_TOTAL (ZACC_ELEMS + MACC_ELEMS + NND)
#define WS_NEED (ACC_BYTE + (size_t)ACC_TOTAL*4)

__device__ __forceinline__ short f2bs(float x){
    __hip_bfloat16 b = __float2bfloat16(x);
    return __builtin_bit_cast(short, b);
}
__device__ __forceinline__ float bs2f(short s){
    unsigned u = ((unsigned)(unsigned short)s) << 16;
    return __builtin_bit_cast(float, u);
}
__device__ __forceinline__ float silu_f(float x){ return x / (1.0f + __expf(-x)); }

// load 8 consecutive f32 (16B-aligned) -> bf16 A/B fragment
__device__ __forceinline__ s8b load8f_bf(const float* p){
    f32x4 a = *(const f32x4*)p;
    f32x4 b = *(const f32x4*)(p + 4);
    s8b r;
    r[0]=f2bs(a[0]); r[1]=f2bs(a[1]); r[2]=f2bs(a[2]); r[3]=f2bs(a[3]);
    r[4]=f2bs(b[0]); r[5]=f2bs(b[1]); r[6]=f2bs(b[2]); r[7]=f2bs(b[3]);
    return r;
}

#define MFMA16(a,b,c) __builtin_amdgcn_mfma_f32_16x16x32_bf16((a),(b),(c),0,0,0)
#define LDS_FENCE() __threadfence_block()

// ---------------- zero accumulators (no SDMA memset — coherence with atomics) ----------------
__global__ __launch_bounds__(256) void zero_kernel(float* __restrict__ p, int n)
{
    int i = blockIdx.x*256 + threadIdx.x;
    int stride = gridDim.x*256;
    for (; i < n; i += stride) p[i] = 0.0f;
}

// ---------------- weight prep ----------------
__global__ __launch_bounds__(256) void fold_kernel(
    const float* __restrict__ We, const float* __restrict__ be,
    const float* __restrict__ Wm1, const float* __restrict__ bm1,
    short* __restrict__ Wm1T, float* __restrict__ bm1f)
{
    int idx = blockIdx.x*256 + threadIdx.x;
    if (idx >= 128*384) return;
    int n = idx / 384, k = idx - n*384;
    float v;
    if (k < 356) v = Wm1[(size_t)k*128 + n];
    else if (k < 372) {
        int j = k - 356; float s = 0.f;
        for (int c = 0; c < 128; c++)
            s += We[j*128 + c] * Wm1[(size_t)(356+c)*128 + n];
        v = s;
    } else v = 0.f;
    Wm1T[(size_t)n*384 + k] = f2bs(v);
    if (k == 0) {
        float s = bm1[n];
        for (int c = 0; c < 128; c++)
            s += be[c] * Wm1[(size_t)(356+c)*128 + n];
        bm1f[n] = s;
    }
}

__global__ __launch_bounds__(256) void prep_kernel(
    const float* __restrict__ Wm2, const float* __restrict__ Wv1,
    const float* __restrict__ Wv2, const float* __restrict__ Ws1,
    const float* __restrict__ Ws2, short* __restrict__ wsb)
{
    int i = blockIdx.x*256 + threadIdx.x;
    if (i < 16384) { int k=i>>7, n=i&127; wsb[WM2T_OFF + n*128 + k] = f2bs(Wm2[i]); return; }
    i -= 16384;
    if (i < 16384) { int k=i>>7, n=i&127; wsb[WV1T_OFF + n*128 + k] = f2bs(Wv1[i]); return; }
    i -= 16384;
    if (i < 10240) { int k=i/80, n=i-k*80; wsb[WV2T_OFF + n*128 + k] = f2bs(Wv2[i]); return; }
    i -= 10240;
    if (i < 32768) { int k=i>>7, n=i&127; wsb[WS1T_OFF + n*256 + k] = f2bs(Ws1[i]); return; }
    i -= 32768;
    if (i < 16384) { int k=i>>7, n=i&127; wsb[WS2T_OFF + n*128 + k] = f2bs(Ws2[i]); return; }
}

// ---------------- edge kernel ----------------
// 128 edges/block, 4 waves, each wave owns 32 edges (2 MFMA A-tiles) end-to-end.
// All LDS rows are wave-private: no __syncthreads, only LDS fences.
__global__ __launch_bounds__(256, 3) void edge_kernel(
    const float* __restrict__ Z, const float* __restrict__ h,
    const int* __restrict__ ei,
    const float* __restrict__ edf, const float* __restrict__ edv,
    const short* __restrict__ Wm1T, const float* __restrict__ bm1f,
    const short* __restrict__ Wm2T, const float* __restrict__ bm2,
    const short* __restrict__ Wv1T, const float* __restrict__ bv1,
    const short* __restrict__ Wv2T, const float* __restrict__ bv2,
    float* __restrict__ Zacc, float* __restrict__ macc, float* __restrict__ cnt)
{
    __shared__ short zsh[EPB*ZR];                 // bf16 Z_ij: [e][d*22 + t*4 + h]
    __shared__ __align__(16) short ssh[EPB*136];  // stage: invar/edf -> act1 -> msg -> act3
    __shared__ int srcs[EPB], dsts[EPB];

    const int tid  = threadIdx.x;
    const int lane = tid & 63;
    const int wave = tid >> 6;
    const int wb   = wave * EPW;
    const int ebase= blockIdx.x * EPB;

    // ---- Phase A1: indices + Z_ij into LDS (2 lanes per edge) ----
    const int row = wb + (lane >> 1);
    const int sub = lane & 1;
    {
        const int e = ebase + row;
        const int s = ei[e], d = ei[NED + e];
        if (sub == 0) {
            srcs[row] = s; dsts[row] = d;
            atomicAdd(cnt + d, 1.0f);
        }
        const float* Zs = Z + (size_t)s*48 + sub*24;
        const float* Zd = Z + (size_t)d*48 + sub*24;
        f32x4 zd0 = *(const f32x4*)(Zd+0),  zd1 = *(const f32x4*)(Zd+4);
        f32x4 zd2 = *(const f32x4*)(Zd+8),  zd3 = *(const f32x4*)(Zd+12);
        f32x4 zd4 = *(const f32x4*)(Zd+16), zd5 = *(const f32x4*)(Zd+20);
        f32x4 zs0 = *(const f32x4*)(Zs+0),  zs1 = *(const f32x4*)(Zs+4);
        f32x4 zs2 = *(const f32x4*)(Zs+8),  zs3 = *(const f32x4*)(Zs+12);
        f32x4 zs4 = *(const f32x4*)(Zs+16), zs5 = *(const f32x4*)(Zs+20);
        float dv[24];
        #pragma unroll
        for (int q = 0; q < 4; q++) {
            dv[q]    = zd0[q]-zs0[q]; dv[4+q]  = zd1[q]-zs1[q];
            dv[8+q]  = zd2[q]-zs2[q]; dv[12+q] = zd3[q]-zs3[q];
            dv[16+q] = zd4[q]-zs4[q]; dv[20+q] = zd5[q]-zs5[q];
        }
        #pragma unroll
        for (int ii = 0; ii < 24; ii++) {
            int i = sub*24 + ii;                   // 0..47 = d*16 + t*4 + h
            int dd = i >> 4, o = i & 15;
            zsh[row*ZR + dd*22 + o] = f2bs(dv[ii]);
        }
        if (sub == 0) {
            #pragma unroll
            for (int dd = 0; dd < 3; dd++) {
                short ev = f2bs(edv[(size_t)e*3 + dd]);
                #pragma unroll
                for (int hh = 0; hh < 4; hh++) zsh[row*ZR + dd*22 + 16 + hh] = ev;
            }
        }
    }
    LDS_FENCE();

    // ---- Phase A2: invariants (Gram symmetry: 15 unique pairs) + edf stage ----
    {
        const int e = ebase + row;
        const int PT[15] = {0,0,0,0,0,1,1,1,1,2,2,2,3,3,4};
        const int PR[15] = {0,1,2,3,4,1,2,3,4,2,3,4,3,4,4};
        float pres[8][4];
        float ssql = 0.f;
        #pragma unroll
        for (int hh = 0; hh < 4; hh++) {
            float zv[3][5];
            #pragma unroll
            for (int dd = 0; dd < 3; dd++)
                #pragma unroll
                for (int tt = 0; tt < 5; tt++)
                    zv[dd][tt] = bs2f(zsh[row*ZR + dd*22 + tt*4 + hh]);
            #pragma unroll
            for (int pp = 0; pp < 8; pp++) {
                int p = sub*8 + pp;
                if (p < 15) {
                    int tt = PT[p], rr = PR[p];
                    float v = zv[0][tt]*zv[0][rr] + zv[1][tt]*zv[1][rr] + zv[2][tt]*zv[2][rr];
                    pres[pp][hh] = v;
                    ssql += (tt == rr ? 1.0f : 2.0f) * v * v;
                }
            }
        }
        float ssq = ssql + __shfl_xor(ssql, 1);
        const float rn = 1.0f / fmaxf(sqrtf(ssq), 1e-12f);
        #pragma unroll
        for (int pp = 0; pp < 8; pp++) {
            int p = sub*8 + pp;
            if (p < 15) {
                int tt = PT[p], rr = PR[p];
                #pragma unroll
                for (int hh = 0; hh < 4; hh++) {
                    short v = f2bs(pres[pp][hh]*rn);
                    ssh[row*136 + tt*20 + rr*4 + hh] = v;
                    if (tt != rr) ssh[row*136 + rr*20 + tt*4 + hh] = v;
                }
            }
        }
        // edf: 16 values, 8 per sub-lane
        {
            const float* ep = edf + (size_t)e*16 + sub*8;
            f32x4 e0 = *(const f32x4*)ep, e1 = *(const f32x4*)(ep+4);
            #pragma unroll
            for (int q = 0; q < 4; q++) {
                ssh[row*136 + 100 + sub*8 + q]     = f2bs(e0[q]);
                ssh[row*136 + 100 + sub*8 + 4 + q] = f2bs(e1[q]);
            }
        }
        #pragma unroll
        for (int k = 0; k < 10; k++)
            ssh[row*136 + 116 + sub + k*2] = 0;
    }
    LDS_FENCE();

    // ---- GEMM phase: 2 A-tiles (32 edges) share every B-fragment load ----
    const int quad = lane >> 4;
    const int c15  = lane & 15;
    const int rA0  = wb + c15;
    const int rA1  = wb + 16 + c15;
    const float* hd0 = h + (size_t)dsts[rA0]*128 + quad*8;
    const float* hs0 = h + (size_t)srcs[rA0]*128 + quad*8;
    const float* hd1 = h + (size_t)dsts[rA1]*128 + quad*8;
    const float* hs1 = h + (size_t)srcs[rA1]*128 + quad*8;
    const short* sA0 = ssh + rA0*136 + quad*8;
    const short* sA1 = ssh + rA1*136 + quad*8;
    const f32x4 z4 = {0.f,0.f,0.f,0.f};

    // Layer 1: x'[384] @ Wm1T' -> 128
    f32x4 acc1[2][8];
    #pragma unroll
    for (int nt = 0; nt < 8; nt++) { acc1[0][nt] = z4; acc1[1][nt] = z4; }
    {
        const short* Bp = Wm1T + (size_t)c15*384 + quad*8;
        #pragma unroll
        for (int ks = 0; ks < 12; ks++) {
            s8b a0, a1;
            if (ks < 4)      { a0 = load8f_bf(hd0 + ks*32);     a1 = load8f_bf(hd1 + ks*32); }
            else if (ks < 8) { a0 = load8f_bf(hs0 + (ks-4)*32); a1 = load8f_bf(hs1 + (ks-4)*32); }
            else             { a0 = *(const s8b*)(sA0 + (ks-8)*32); a1 = *(const s8b*)(sA1 + (ks-8)*32); }
            #pragma unroll
            for (int nt = 0; nt < 8; nt++) {
                s8b b = *(const s8b*)(Bp + nt*(16*384) + ks*32);
                acc1[0][nt] = MFMA16(a0, b, acc1[0][nt]);
                acc1[1][nt] = MFMA16(a1, b, acc1[1][nt]);
            }
        }
    }
    LDS_FENCE();
    #pragma unroll
    for (int nt = 0; nt < 8; nt++) {
        const int col = nt*16 + c15;
        const float bias = bm1f[col];
        #pragma unroll
        for (int tl = 0; tl < 2; tl++)
            #pragma unroll
            for (int r = 0; r < 4; r++)
                ssh[(wb + tl*16 + quad*4 + r)*136 + col] = f2bs(silu_f(acc1[tl][nt][r] + bias));
    }
    LDS_FENCE();

    // Layer 2: act1 @ Wm2 -> msg ; atomic-add msg (f32) to macc
    f32x4 acc2[2][8];
    #pragma unroll
    for (int nt = 0; nt < 8; nt++) { acc2[0][nt] = z4; acc2[1][nt] = z4; }
    {
        const short* Bp = Wm2T + (size_t)c15*128 + quad*8;
        #pragma unroll
        for (int ks = 0; ks < 4; ks++) {
            s8b a0 = *(const s8b*)(sA0 + ks*32);
            s8b a1 = *(const s8b*)(sA1 + ks*32);
            #pragma unroll
            for (int nt = 0; nt < 8; nt++) {
                s8b b = *(const s8b*)(Bp + nt*(16*128) + ks*32);
                acc2[0][nt] = MFMA16(a0, b, acc2[0][nt]);
                acc2[1][nt] = MFMA16(a1, b, acc2[1][nt]);
            }
        }
    }
    LDS_FENCE();
    #pragma unroll
    for (int nt = 0; nt < 8; nt++) {
        const int col = nt*16 + c15;
        const float bias = bm2[col];
        #pragma unroll
        for (int tl = 0; tl < 2; tl++)
            #pragma unroll
            for (int r = 0; r < 4; r++) {
                const int rw = wb + tl*16 + quad*4 + r;
                float v = silu_f(acc2[tl][nt][r] + bias);
                atomicAdd(macc + (size_t)dsts[rw]*128 + col, v);
                ssh[rw*136 + col] = f2bs(v);
            }
    }
    LDS_FENCE();

    // Layer 3: msg @ Wv1 -> act3
    f32x4 acc3[2][8];
    #pragma unroll
    for (int nt = 0; nt < 8; nt++) { acc3[0][nt] = z4; acc3[1][nt] = z4; }
    {
        const short* Bp = Wv1T + (size_t)c15*128 + quad*8;
        #pragma unroll
        for (int ks = 0; ks < 4; ks++) {
            s8b a0 = *(const s8b*)(sA0 + ks*32);
            s8b a1 = *(const s8b*)(sA1 + ks*32);
            #pragma unroll
            for (int nt = 0; nt < 8; nt++) {
                s8b b = *(const s8b*)(Bp + nt*(16*128) + ks*32);
                acc3[0][nt] = MFMA16(a0, b, acc3[0][nt]);
                acc3[1][nt] = MFMA16(a1, b, acc3[1][nt]);
            }
        }
    }
    LDS_FENCE();
    #pragma unroll
    for (int nt = 0; nt < 8; nt++) {
        const int col = nt*16 + c15;
        const float bias = bv1[col];
        #pragma unroll
        for (int tl = 0; tl < 2; tl++)
            #pragma unroll
            for (int r = 0; r < 4; r++)
                ssh[(wb + tl*16 + quad*4 + r)*136 + col] = f2bs(silu_f(acc3[tl][nt][r] + bias));
    }
    LDS_FENCE();

    // Layer 4: act3 @ Wv2 -> basis[80] ; contract with Z_ij ; atomic to Zacc
    f32x4 acc4[2][5];
    #pragma unroll
    for (int nt = 0; nt < 5; nt++) { acc4[0][nt] = z4; acc4[1][nt] = z4; }
    {
        const short* Bp = Wv2T + (size_t)c15*128 + quad*8;
        #pragma unroll
        for (int ks = 0; ks < 4; ks++) {
            s8b a0 = *(const s8b*)(sA0 + ks*32);
            s8b a1 = *(const s8b*)(sA1 + ks*32);
            #pragma unroll
            for (int nt = 0; nt < 5; nt++) {
                s8b b = *(const s8b*)(Bp + nt*(16*128) + ks*32);
                acc4[0][nt] = MFMA16(a0, b, acc4[0][nt]);
                acc4[1][nt] = MFMA16(a1, b, acc4[1][nt]);
            }
        }
    }
    {
        const int hh = c15 & 3;                   // basis col = t*16 + (k*4+h); c15 = k*4+h
        float bs[5];
        #pragma unroll
        for (int t = 0; t < 5; t++) bs[t] = bv2[t*16 + c15];
        #pragma unroll
        for (int tl = 0; tl < 2; tl++)
            #pragma unroll
            for (int r = 0; r < 4; r++) {
                const int rw = wb + tl*16 + quad*4 + r;
                const int eg = dsts[rw];
                float bt[5];
                #pragma unroll
                for (int t = 0; t < 5; t++) bt[t] = acc4[tl][t][r] + bs[t];
                #pragma unroll
                for (int dd = 0; dd < 3; dd++) {
                    float s0 = 0.f;
                    #pragma unroll
                    for (int t = 0; t < 5; t++)
                        s0 += bs2f(zsh[rw*ZR + dd*22 + t*4 + hh]) * bt[t];
                    atomicAdd(Zacc + (size_t)eg*48 + dd*16 + c15, s0);
                }
            }
    }
}

// ---------------- node kernel ----------------
__global__ __launch_bounds__(256) void node_kernel(
    const float* __restrict__ h,
    const short* __restrict__ Ws1T, const float* __restrict__ bs1,
    const short* __restrict__ Ws2T, const float* __restrict__ bs2,
    const float* __restrict__ Zacc, const float* __restrict__ macc,
    const float* __restrict__ cnt, float* __restrict__ out)
{
    __shared__ __align__(16) short ssh[64*136];   // m stage -> act1
    const int tid = threadIdx.x, lane = tid & 63, wave = tid >> 6;
    const int mb = wave*16;
    const int nbase = blockIdx.x * 64;

    // Z_out = Zacc / max(cnt,1)
    for (int i = tid; i < 64*48; i += 256) {
        int nl = i / 48, c2 = i - nl*48;
        int nd = nbase + nl;
        if (nd < NND) {
            float ct = fmaxf(cnt[nd], 1.0f);
            out[(size_t)nd*48 + c2] = Zacc[(size_t)nd*48 + c2] / ct;
        }
    }

    // stage m (bf16)
    {
        const int row = mb + (lane >> 2);
        const int sub = lane & 3;
        int nd = nbase + row; if (nd >= NND) nd = 0;
        const float* mr = macc + (size_t)nd*128 + sub*32;
        #pragma unroll
        for (int j = 0; j < 8; j++) {
            f32x4 v = *(const f32x4*)(mr + j*4);
            int cb = row*136 + sub*32 + j*4;
            ssh[cb+0] = f2bs(v[0]); ssh[cb+1] = f2bs(v[1]);
            ssh[cb+2] = f2bs(v[2]); ssh[cb+3] = f2bs(v[3]);
        }
    }
    __syncthreads();

    const int quad = lane >> 4, c15 = lane & 15;
    const int rA = mb + c15;
    int ndA = nbase + rA; if (ndA >= NND) ndA = 0;   // clamp; stores guarded
    const float* hA = h + (size_t)ndA*128 + quad*8;
    const short* sA = ssh + rA*136 + quad*8;
    const f32x4 z4 = {0.f,0.f,0.f,0.f};

    // GEMM1: [h | m] (K=256) @ Ws1
    f32x4 acc1[8];
    #pragma unroll
    for (int nt = 0; nt < 8; nt++) acc1[nt] = z4;
    {
        const short* Bp = Ws1T + (size_t)c15*256 + quad*8;
        #pragma unroll
        for (int ks = 0; ks < 8; ks++) {
            s8b a;
            if (ks < 4) a = load8f_bf(hA + ks*32);
            else        a = *(const s8b*)(sA + (ks-4)*32);
            #pragma unroll
            for (int nt = 0; nt < 8; nt++) {
                s8b b = *(const s8b*)(Bp + nt*(16*256) + ks*32);
                acc1[nt] = MFMA16(a, b, acc1[nt]);
            }
        }
    }
    __syncthreads();
    #pragma unroll
    for (int nt = 0; nt < 8; nt++) {
        const int col = nt*16 + c15;
        const float bias = bs1[col];
        #pragma unroll
        for (int r = 0; r < 4; r++)
            ssh[(mb + quad*4 + r)*136 + col] = f2bs(silu_f(acc1[nt][r] + bias));
    }
    __syncthreads();

    // GEMM2: act @ Ws2 -> h_out
    f32x4 acc2[8];
    #pragma unroll
    for (int nt = 0; nt < 8; nt++) acc2[nt] = z4;
    {
        const short* Bp = Ws2T + (size_t)c15*128 + quad*8;
        #pragma unroll
        for (int ks = 0; ks < 4; ks++) {
            s8b a = *(const s8b*)(sA + ks*32);
            #pragma unroll
            for (int nt = 0; nt < 8; nt++) {
                s8b b = *(const s8b*)(Bp + nt*(16*128) + ks*32);
                acc2[nt] = MFMA16(a, b, acc2[nt]);
            }
        }
    }
    {
        float* oh = out + (size_t)NND*48;
        #pragma unroll
        for (int nt = 0; nt < 8; nt++) {
            const int col = nt*16 + c15;
            const float bias = bs2[col];
            #pragma unroll
            for (int r = 0; r < 4; r++) {
                const int rw = mb + quad*4 + r;
                const int nd = nbase + rw;
                if (nd < NND)
                    oh[(size_t)nd*128 + col] = acc2[nt][r] + bias;
            }
        }
    }
}

extern "C" void kernel_launch(void* const* d_in, const int* in_sizes, int n_in,
                              void* d_out, int out_size, void* d_ws, size_t ws_size,
                              hipStream_t stream)
{
    const float* Z   = (const float*)d_in[0];
    const float* h   = (const float*)d_in[1];
    const int*   ei  = (const int*)d_in[2];
    const float* edf = (const float*)d_in[3];
    const float* edv = (const float*)d_in[4];
    // d_in[5] = edge_distance (unused by reference)
    const float* We  = (const float*)d_in[6];
    const float* be  = (const float*)d_in[7];
    const float* Wm1 = (const float*)d_in[8];
    const float* bm1 = (const float*)d_in[9];
    const float* Wm2 = (const float*)d_in[10];
    const float* bm2 = (const float*)d_in[11];
    const float* Wv1 = (const float*)d_in[12];
    const float* bv1 = (const float*)d_in[13];
    const float* Wv2 = (const float*)d_in[14];
    const float* bv2 = (const float*)d_in[15];
    const float* Ws1 = (const float*)d_in[16];
    const float* bs1 = (const float*)d_in[17];
    const float* Ws2 = (const float*)d_in[18];
    const float* bs2 = (const float*)d_in[19];

    if (ws_size < WS_NEED) return;

    char* wsc = (char*)d_ws;
    short* wsb = (short*)d_ws;
    float* bm1f = (float*)(wsc + BM1F_BYTE);
    float* Zacc = (float*)(wsc + ACC_BYTE);
    float* macc = Zacc + ZACC_ELEMS;
    float* cnt  = macc + MACC_ELEMS;

    zero_kernel<<<2048, 256, 0, stream>>>(Zacc, ACC_TOTAL);
    fold_kernel<<<192, 256, 0, stream>>>(We, be, Wm1, bm1, wsb + WM1T_OFF, bm1f);
    prep_kernel<<<360, 256, 0, stream>>>(Wm2, Wv1, Wv2, Ws1, Ws2, wsb);
    edge_kernel<<<NED/EPB, 256, 0, stream>>>(Z, h, ei, edf, edv,
        wsb + WM1T_OFF, bm1f, wsb + WM2T_OFF, bm2, wsb + WV1T_OFF, bv1,
        wsb + WV2T_OFF, bv2, Zacc, macc, cnt);
    node_kernel<<<(NND + 63)/64, 256, 0, stream>>>(h, wsb + WS1T_OFF, bs1,
        wsb + WS2T_OFF, bs2, Zacc, macc, cnt, (float*)d_out);
}

// Round 5
// 1133.771 us; speedup vs baseline: 1.4302x; 1.0558x over previous
//
#include <hip/hip_runtime.h>
#include <hip/hip_bf16.h>

typedef __attribute__((ext_vector_type(8))) short s8b;     // 8 bf16 (4 VGPRs)
typedef __attribute__((ext_vector_type(4))) float f32x4;   // MFMA accumulator
typedef __attribute__((ext_vector_type(4))) unsigned u32x4;

#define NND 50000
#define NED 800000
#define EPB 128     // edges per block
#define EPW 32      // edges per wave
#define ZR  66      // zsh row stride in shorts (bank-spread)

// workspace layout (bf16-element offsets for weights, byte offsets for f32)
#define WM1T_OFF 0         // [128][384] folded+transposed Wm1'
#define WM2T_OFF 49152     // [128][128]
#define WV1T_OFF 65536     // [128][128]
#define WV2T_OFF 81920     // [80][128]
#define WS1T_OFF 92160     // [128][256]
#define WS2T_OFF 124928    // [128][128]
#define BM1F_BYTE 282624   // 128 f32 (folded bias)
#define ACC_BYTE  283136   // f32 accumulators start (16B aligned)
#define ZACC_ELEMS (NND*48)
#define MACC_ELEMS (NND*128)
#define ACC_TOTAL (ZACC_ELEMS + MACC_ELEMS + NND)
#define WS_NEED (ACC_BYTE + (size_t)ACC_TOTAL*4)

// accurate RNE cvt (weight prep only)
__device__ __forceinline__ short f2bs(float x){
    __hip_bfloat16 b = __float2bfloat16(x);
    return __builtin_bit_cast(short, b);
}
// fast cvt: round-half-up, 2 VALU ops (finite inputs only)
__device__ __forceinline__ short f2bs_fast(float x){
    unsigned u = __builtin_bit_cast(unsigned, x) + 0x8000u;
    return (short)(u >> 16);
}
// pack 2 floats -> 2 bf16 in one dword (lo=a, hi=b): add,add,v_perm = 3 ops
__device__ __forceinline__ unsigned pk2(float a, float b){
    unsigned ua = __builtin_bit_cast(unsigned, a) + 0x8000u;
    unsigned ub = __builtin_bit_cast(unsigned, b) + 0x8000u;
    return __builtin_amdgcn_perm(ub, ua, 0x07060302u);
}
__device__ __forceinline__ float bs2f(short s){
    unsigned u = ((unsigned)(unsigned short)s) << 16;
    return __builtin_bit_cast(float, u);
}
__device__ __forceinline__ float silu_f(float x){ return x / (1.0f + __expf(-x)); }

// load 8 consecutive f32 (16B-aligned) -> bf16 A/B fragment (12 VALU ops)
__device__ __forceinline__ s8b load8f_bf(const float* p){
    f32x4 a = *(const f32x4*)p;
    f32x4 b = *(const f32x4*)(p + 4);
    u32x4 r;
    r[0] = pk2(a[0], a[1]); r[1] = pk2(a[2], a[3]);
    r[2] = pk2(b[0], b[1]); r[3] = pk2(b[2], b[3]);
    return __builtin_bit_cast(s8b, r);
}

#define MFMA16(a,b,c) __builtin_amdgcn_mfma_f32_16x16x32_bf16((a),(b),(c),0,0,0)
// LDS-only ordering: do NOT drain vmcnt (atomics must free-run)
#define LDS_FENCE() asm volatile("s_waitcnt lgkmcnt(0)" ::: "memory")

// ---------------- zero accumulators (no SDMA memset — coherence with atomics) ----------------
__global__ __launch_bounds__(256) void zero_kernel(float* __restrict__ p, int n)
{
    int i = blockIdx.x*256 + threadIdx.x;
    int stride = gridDim.x*256;
    for (; i < n; i += stride) p[i] = 0.0f;
}

// ---------------- weight prep ----------------
__global__ __launch_bounds__(256) void fold_kernel(
    const float* __restrict__ We, const float* __restrict__ be,
    const float* __restrict__ Wm1, const float* __restrict__ bm1,
    short* __restrict__ Wm1T, float* __restrict__ bm1f)
{
    int idx = blockIdx.x*256 + threadIdx.x;
    if (idx >= 128*384) return;
    int n = idx / 384, k = idx - n*384;
    float v;
    if (k < 356) v = Wm1[(size_t)k*128 + n];
    else if (k < 372) {
        int j = k - 356; float s = 0.f;
        for (int c = 0; c < 128; c++)
            s += We[j*128 + c] * Wm1[(size_t)(356+c)*128 + n];
        v = s;
    } else v = 0.f;
    Wm1T[(size_t)n*384 + k] = f2bs(v);
    if (k == 0) {
        float s = bm1[n];
        for (int c = 0; c < 128; c++)
            s += be[c] * Wm1[(size_t)(356+c)*128 + n];
        bm1f[n] = s;
    }
}

__global__ __launch_bounds__(256) void prep_kernel(
    const float* __restrict__ Wm2, const float* __restrict__ Wv1,
    const float* __restrict__ Wv2, const float* __restrict__ Ws1,
    const float* __restrict__ Ws2, short* __restrict__ wsb)
{
    int i = blockIdx.x*256 + threadIdx.x;
    if (i < 16384) { int k=i>>7, n=i&127; wsb[WM2T_OFF + n*128 + k] = f2bs(Wm2[i]); return; }
    i -= 16384;
    if (i < 16384) { int k=i>>7, n=i&127; wsb[WV1T_OFF + n*128 + k] = f2bs(Wv1[i]); return; }
    i -= 16384;
    if (i < 10240) { int k=i/80, n=i-k*80; wsb[WV2T_OFF + n*128 + k] = f2bs(Wv2[i]); return; }
    i -= 10240;
    if (i < 32768) { int k=i>>7, n=i&127; wsb[WS1T_OFF + n*256 + k] = f2bs(Ws1[i]); return; }
    i -= 32768;
    if (i < 16384) { int k=i>>7, n=i&127; wsb[WS2T_OFF + n*128 + k] = f2bs(Ws2[i]); return; }
}

// ---------------- edge kernel ----------------
// 128 edges/block, 4 waves, each wave owns 32 edges (2 MFMA A-tiles) end-to-end.
// All LDS rows are wave-private: no __syncthreads, only lgkm fences.
__global__ __launch_bounds__(256, 3) void edge_kernel(
    const float* __restrict__ Z, const float* __restrict__ h,
    const int* __restrict__ ei,
    const float* __restrict__ edf, const float* __restrict__ edv,
    const short* __restrict__ Wm1T, const float* __restrict__ bm1f,
    const short* __restrict__ Wm2T, const float* __restrict__ bm2,
    const short* __restrict__ Wv1T, const float* __restrict__ bv1,
    const short* __restrict__ Wv2T, const float* __restrict__ bv2,
    float* __restrict__ Zacc, float* __restrict__ macc, float* __restrict__ cnt)
{
    __shared__ short zsh[EPB*ZR];                 // bf16 Z_ij: [e][d*22 + t*4 + h]
    __shared__ __align__(16) short ssh[EPB*136];  // stage: invar/edf -> act1 -> msg -> act3
    __shared__ int srcs[EPB], dsts[EPB];

    const int tid  = threadIdx.x;
    const int lane = tid & 63;
    const int wave = tid >> 6;
    const int wb   = wave * EPW;
    const int ebase= blockIdx.x * EPB;

    // ---- Phase A1: indices + Z_ij into LDS (2 lanes per edge) ----
    const int row = wb + (lane >> 1);
    const int sub = lane & 1;
    {
        const int e = ebase + row;
        const int s = ei[e], d = ei[NED + e];
        if (sub == 0) {
            srcs[row] = s; dsts[row] = d;
            atomicAdd(cnt + d, 1.0f);
        }
        const float* Zs = Z + (size_t)s*48 + sub*24;
        const float* Zd = Z + (size_t)d*48 + sub*24;
        f32x4 zd0 = *(const f32x4*)(Zd+0),  zd1 = *(const f32x4*)(Zd+4);
        f32x4 zd2 = *(const f32x4*)(Zd+8),  zd3 = *(const f32x4*)(Zd+12);
        f32x4 zd4 = *(const f32x4*)(Zd+16), zd5 = *(const f32x4*)(Zd+20);
        f32x4 zs0 = *(const f32x4*)(Zs+0),  zs1 = *(const f32x4*)(Zs+4);
        f32x4 zs2 = *(const f32x4*)(Zs+8),  zs3 = *(const f32x4*)(Zs+12);
        f32x4 zs4 = *(const f32x4*)(Zs+16), zs5 = *(const f32x4*)(Zs+20);
        float dv[24];
        #pragma unroll
        for (int q = 0; q < 4; q++) {
            dv[q]    = zd0[q]-zs0[q]; dv[4+q]  = zd1[q]-zs1[q];
            dv[8+q]  = zd2[q]-zs2[q]; dv[12+q] = zd3[q]-zs3[q];
            dv[16+q] = zd4[q]-zs4[q]; dv[20+q] = zd5[q]-zs5[q];
        }
        #pragma unroll
        for (int ii = 0; ii < 24; ii += 2) {
            int i = sub*24 + ii;                   // 0..47 = d*16 + t*4 + h
            int dd = i >> 4, o = i & 15;           // o even; pair stays in same dd
            *(unsigned*)(&zsh[row*ZR + dd*22 + o]) = pk2(dv[ii], dv[ii+1]);
        }
        if (sub == 0) {
            #pragma unroll
            for (int dd = 0; dd < 3; dd++) {
                float ev = edv[(size_t)e*3 + dd];
                unsigned evp = pk2(ev, ev);
                *(unsigned*)(&zsh[row*ZR + dd*22 + 16]) = evp;
                *(unsigned*)(&zsh[row*ZR + dd*22 + 18]) = evp;
            }
        }
    }
    LDS_FENCE();

    // ---- Phase A2: invariants (Gram symmetry: 15 unique pairs) + edf stage ----
    {
        const int e = ebase + row;
        const int PT[15] = {0,0,0,0,0,1,1,1,1,2,2,2,3,3,4};
        const int PR[15] = {0,1,2,3,4,1,2,3,4,2,3,4,3,4,4};
        float pres[8][4];
        float ssql = 0.f;
        #pragma unroll
        for (int hh = 0; hh < 4; hh++) {
            float zv[3][5];
            #pragma unroll
            for (int dd = 0; dd < 3; dd++)
                #pragma unroll
                for (int tt = 0; tt < 5; tt++)
                    zv[dd][tt] = bs2f(zsh[row*ZR + dd*22 + tt*4 + hh]);
            #pragma unroll
            for (int pp = 0; pp < 8; pp++) {
                int p = sub*8 + pp;
                if (p < 15) {
                    int tt = PT[p], rr = PR[p];
                    float v = zv[0][tt]*zv[0][rr] + zv[1][tt]*zv[1][rr] + zv[2][tt]*zv[2][rr];
                    pres[pp][hh] = v;
                    ssql += (tt == rr ? 1.0f : 2.0f) * v * v;
                }
            }
        }
        float ssq = ssql + __shfl_xor(ssql, 1);
        const float rn = 1.0f / fmaxf(sqrtf(ssq), 1e-12f);
        #pragma unroll
        for (int pp = 0; pp < 8; pp++) {
            int p = sub*8 + pp;
            if (p < 15) {
                int tt = PT[p], rr = PR[p];
                #pragma unroll
                for (int hh = 0; hh < 4; hh++) {
                    short v = f2bs_fast(pres[pp][hh]*rn);
                    ssh[row*136 + tt*20 + rr*4 + hh] = v;
                    if (tt != rr) ssh[row*136 + rr*20 + tt*4 + hh] = v;
                }
            }
        }
        // edf: 16 values, 8 per sub-lane, packed b32 writes
        {
            const float* ep = edf + (size_t)e*16 + sub*8;
            f32x4 e0 = *(const f32x4*)ep, e1 = *(const f32x4*)(ep+4);
            int cb = row*136 + 100 + sub*8;
            *(unsigned*)(&ssh[cb+0]) = pk2(e0[0], e0[1]);
            *(unsigned*)(&ssh[cb+2]) = pk2(e0[2], e0[3]);
            *(unsigned*)(&ssh[cb+4]) = pk2(e1[0], e1[1]);
            *(unsigned*)(&ssh[cb+6]) = pk2(e1[2], e1[3]);
        }
        #pragma unroll
        for (int k = 0; k < 5; k++)
            *(unsigned*)(&ssh[row*136 + 116 + (sub*5 + k)*2]) = 0;
    }
    LDS_FENCE();

    // ---- GEMM phase: 2 A-tiles (32 edges) share every B-fragment load ----
    const int quad = lane >> 4;
    const int c15  = lane & 15;
    const int rA0  = wb + c15;
    const int rA1  = wb + 16 + c15;
    const float* hd0 = h + (size_t)dsts[rA0]*128 + quad*8;
    const float* hs0 = h + (size_t)srcs[rA0]*128 + quad*8;
    const float* hd1 = h + (size_t)dsts[rA1]*128 + quad*8;
    const float* hs1 = h + (size_t)srcs[rA1]*128 + quad*8;
    const short* sA0 = ssh + rA0*136 + quad*8;
    const short* sA1 = ssh + rA1*136 + quad*8;
    const f32x4 z4 = {0.f,0.f,0.f,0.f};

    // Layer 1: x'[384] @ Wm1T' -> 128
    f32x4 acc1[2][8];
    #pragma unroll
    for (int nt = 0; nt < 8; nt++) { acc1[0][nt] = z4; acc1[1][nt] = z4; }
    {
        const short* Bp = Wm1T + (size_t)c15*384 + quad*8;
        #pragma unroll
        for (int ks = 0; ks < 12; ks++) {
            s8b a0, a1;
            if (ks < 4)      { a0 = load8f_bf(hd0 + ks*32);     a1 = load8f_bf(hd1 + ks*32); }
            else if (ks < 8) { a0 = load8f_bf(hs0 + (ks-4)*32); a1 = load8f_bf(hs1 + (ks-4)*32); }
            else             { a0 = *(const s8b*)(sA0 + (ks-8)*32); a1 = *(const s8b*)(sA1 + (ks-8)*32); }
            #pragma unroll
            for (int nt = 0; nt < 8; nt++) {
                s8b b = *(const s8b*)(Bp + nt*(16*384) + ks*32);
                acc1[0][nt] = MFMA16(a0, b, acc1[0][nt]);
                acc1[1][nt] = MFMA16(a1, b, acc1[1][nt]);
            }
        }
    }
    LDS_FENCE();
    #pragma unroll
    for (int nt = 0; nt < 8; nt++) {
        const int col = nt*16 + c15;
        const float bias = bm1f[col];
        #pragma unroll
        for (int tl = 0; tl < 2; tl++)
            #pragma unroll
            for (int r = 0; r < 4; r++)
                ssh[(wb + tl*16 + quad*4 + r)*136 + col] = f2bs_fast(silu_f(acc1[tl][nt][r] + bias));
    }
    LDS_FENCE();

    // Layer 2: act1 @ Wm2 -> msg ; atomic-add msg (f32) to macc
    f32x4 acc2[2][8];
    #pragma unroll
    for (int nt = 0; nt < 8; nt++) { acc2[0][nt] = z4; acc2[1][nt] = z4; }
    {
        const short* Bp = Wm2T + (size_t)c15*128 + quad*8;
        #pragma unroll
        for (int ks = 0; ks < 4; ks++) {
            s8b a0 = *(const s8b*)(sA0 + ks*32);
            s8b a1 = *(const s8b*)(sA1 + ks*32);
            #pragma unroll
            for (int nt = 0; nt < 8; nt++) {
                s8b b = *(const s8b*)(Bp + nt*(16*128) + ks*32);
                acc2[0][nt] = MFMA16(a0, b, acc2[0][nt]);
                acc2[1][nt] = MFMA16(a1, b, acc2[1][nt]);
            }
        }
    }
    LDS_FENCE();
    #pragma unroll
    for (int nt = 0; nt < 8; nt++) {
        const int col = nt*16 + c15;
        const float bias = bm2[col];
        #pragma unroll
        for (int tl = 0; tl < 2; tl++)
            #pragma unroll
            for (int r = 0; r < 4; r++) {
                const int rw = wb + tl*16 + quad*4 + r;
                float v = silu_f(acc2[tl][nt][r] + bias);
                atomicAdd(macc + (size_t)dsts[rw]*128 + col, v);
                ssh[rw*136 + col] = f2bs_fast(v);
            }
    }
    LDS_FENCE();

    // Layer 3: msg @ Wv1 -> act3
    f32x4 acc3[2][8];
    #pragma unroll
    for (int nt = 0; nt < 8; nt++) { acc3[0][nt] = z4; acc3[1][nt] = z4; }
    {
        const short* Bp = Wv1T + (size_t)c15*128 + quad*8;
        #pragma unroll
        for (int ks = 0; ks < 4; ks++) {
            s8b a0 = *(const s8b*)(sA0 + ks*32);
            s8b a1 = *(const s8b*)(sA1 + ks*32);
            #pragma unroll
            for (int nt = 0; nt < 8; nt++) {
                s8b b = *(const s8b*)(Bp + nt*(16*128) + ks*32);
                acc3[0][nt] = MFMA16(a0, b, acc3[0][nt]);
                acc3[1][nt] = MFMA16(a1, b, acc3[1][nt]);
            }
        }
    }
    LDS_FENCE();
    #pragma unroll
    for (int nt = 0; nt < 8; nt++) {
        const int col = nt*16 + c15;
        const float bias = bv1[col];
        #pragma unroll
        for (int tl = 0; tl < 2; tl++)
            #pragma unroll
            for (int r = 0; r < 4; r++)
                ssh[(wb + tl*16 + quad*4 + r)*136 + col] = f2bs_fast(silu_f(acc3[tl][nt][r] + bias));
    }
    LDS_FENCE();

    // Layer 4: act3 @ Wv2 -> basis[80] ; contract with Z_ij ; atomic to Zacc
    f32x4 acc4[2][5];
    #pragma unroll
    for (int nt = 0; nt < 5; nt++) { acc4[0][nt] = z4; acc4[1][nt] = z4; }
    {
        const short* Bp = Wv2T + (size_t)c15*128 + quad*8;
        #pragma unroll
        for (int ks = 0; ks < 4; ks++) {
            s8b a0 = *(const s8b*)(sA0 + ks*32);
            s8b a1 = *(const s8b*)(sA1 + ks*32);
            #pragma unroll
            for (int nt = 0; nt < 5; nt++) {
                s8b b = *(const s8b*)(Bp + nt*(16*128) + ks*32);
                acc4[0][nt] = MFMA16(a0, b, acc4[0][nt]);
                acc4[1][nt] = MFMA16(a1, b, acc4[1][nt]);
            }
        }
    }
    {
        const int hh = c15 & 3;                   // basis col = t*16 + (k*4+h); c15 = k*4+h
        float bs[5];
        #pragma unroll
        for (int t = 0; t < 5; t++) bs[t] = bv2[t*16 + c15];
        #pragma unroll
        for (int tl = 0; tl < 2; tl++)
            #pragma unroll
            for (int r = 0; r < 4; r++) {
                const int rw = wb + tl*16 + quad*4 + r;
                const int eg = dsts[rw];
                float bt[5];
                #pragma unroll
                for (int t = 0; t < 5; t++) bt[t] = acc4[tl][t][r] + bs[t];
                #pragma unroll
                for (int dd = 0; dd < 3; dd++) {
                    float s0 = 0.f;
                    #pragma unroll
                    for (int t = 0; t < 5; t++)
                        s0 += bs2f(zsh[rw*ZR + dd*22 + t*4 + hh]) * bt[t];
                    atomicAdd(Zacc + (size_t)eg*48 + dd*16 + c15, s0);
                }
            }
    }
}

// ---------------- node kernel ----------------
__global__ __launch_bounds__(256) void node_kernel(
    const float* __restrict__ h,
    const short* __restrict__ Ws1T, const float* __restrict__ bs1,
    const short* __restrict__ Ws2T, const float* __restrict__ bs2,
    const float* __restrict__ Zacc, const float* __restrict__ macc,
    const float* __restrict__ cnt, float* __restrict__ out)
{
    __shared__ __align__(16) short ssh[64*136];   // m stage -> act1
    const int tid = threadIdx.x, lane = tid & 63, wave = tid >> 6;
    const int mb = wave*16;
    const int nbase = blockIdx.x * 64;

    // Z_out = Zacc / max(cnt,1)
    for (int i = tid; i < 64*48; i += 256) {
        int nl = i / 48, c2 = i - nl*48;
        int nd = nbase + nl;
        if (nd < NND) {
            float ct = fmaxf(cnt[nd], 1.0f);
            out[(size_t)nd*48 + c2] = Zacc[(size_t)nd*48 + c2] / ct;
        }
    }

    // stage m (bf16), wave-private rows
    {
        const int row = mb + (lane >> 2);
        const int sub = lane & 3;
        int nd = nbase + row; if (nd >= NND) nd = 0;
        const float* mr = macc + (size_t)nd*128 + sub*32;
        #pragma unroll
        for (int j = 0; j < 8; j++) {
            f32x4 v = *(const f32x4*)(mr + j*4);
            int cb = row*136 + sub*32 + j*4;
            *(unsigned*)(&ssh[cb+0]) = pk2(v[0], v[1]);
            *(unsigned*)(&ssh[cb+2]) = pk2(v[2], v[3]);
        }
    }
    LDS_FENCE();

    const int quad = lane >> 4, c15 = lane & 15;
    const int rA = mb + c15;
    int ndA = nbase + rA; if (ndA >= NND) ndA = 0;   // clamp; stores guarded
    const float* hA = h + (size_t)ndA*128 + quad*8;
    const short* sA = ssh + rA*136 + quad*8;
    const f32x4 z4 = {0.f,0.f,0.f,0.f};

    // GEMM1: [h | m] (K=256) @ Ws1
    f32x4 acc1[8];
    #pragma unroll
    for (int nt = 0; nt < 8; nt++) acc1[nt] = z4;
    {
        const short* Bp = Ws1T + (size_t)c15*256 + quad*8;
        #pragma unroll
        for (int ks = 0; ks < 8; ks++) {
            s8b a;
            if (ks < 4) a = load8f_bf(hA + ks*32);
            else        a = *(const s8b*)(sA + (ks-4)*32);
            #pragma unroll
            for (int nt = 0; nt < 8; nt++) {
                s8b b = *(const s8b*)(Bp + nt*(16*256) + ks*32);
                acc1[nt] = MFMA16(a, b, acc1[nt]);
            }
        }
    }
    LDS_FENCE();
    #pragma unroll
    for (int nt = 0; nt < 8; nt++) {
        const int col = nt*16 + c15;
        const float bias = bs1[col];
        #pragma unroll
        for (int r = 0; r < 4; r++)
            ssh[(mb + quad*4 + r)*136 + col] = f2bs_fast(silu_f(acc1[nt][r] + bias));
    }
    LDS_FENCE();

    // GEMM2: act @ Ws2 -> h_out
    f32x4 acc2[8];
    #pragma unroll
    for (int nt = 0; nt < 8; nt++) acc2[nt] = z4;
    {
        const short* Bp = Ws2T + (size_t)c15*128 + quad*8;
        #pragma unroll
        for (int ks = 0; ks < 4; ks++) {
            s8b a = *(const s8b*)(sA + ks*32);
            #pragma unroll
            for (int nt = 0; nt < 8; nt++) {
                s8b b = *(const s8b*)(Bp + nt*(16*128) + ks*32);
                acc2[nt] = MFMA16(a, b, acc2[nt]);
            }
        }
    }
    {
        float* oh = out + (size_t)NND*48;
        #pragma unroll
        for (int nt = 0; nt < 8; nt++) {
            const int col = nt*16 + c15;
            const float bias = bs2[col];
            #pragma unroll
            for (int r = 0; r < 4; r++) {
                const int rw = mb + quad*4 + r;
                const int nd = nbase + rw;
                if (nd < NND)
                    oh[(size_t)nd*128 + col] = acc2[nt][r] + bias;
            }
        }
    }
}

extern "C" void kernel_launch(void* const* d_in, const int* in_sizes, int n_in,
                              void* d_out, int out_size, void* d_ws, size_t ws_size,
                              hipStream_t stream)
{
    const float* Z   = (const float*)d_in[0];
    const float* h   = (const float*)d_in[1];
    const int*   ei  = (const int*)d_in[2];
    const float* edf = (const float*)d_in[3];
    const float* edv = (const float*)d_in[4];
    // d_in[5] = edge_distance (unused by reference)
    const float* We  = (const float*)d_in[6];
    const float* be  = (const float*)d_in[7];
    const float* Wm1 = (const float*)d_in[8];
    const float* bm1 = (const float*)d_in[9];
    const float* Wm2 = (const float*)d_in[10];
    const float* bm2 = (const float*)d_in[11];
    const float* Wv1 = (const float*)d_in[12];
    const float* bv1 = (const float*)d_in[13];
    const float* Wv2 = (const float*)d_in[14];
    const float* bv2 = (const float*)d_in[15];
    const float* Ws1 = (const float*)d_in[16];
    const float* bs1 = (const float*)d_in[17];
    const float* Ws2 = (const float*)d_in[18];
    const float* bs2 = (const float*)d_in[19];

    if (ws_size < WS_NEED) return;

    char* wsc = (char*)d_ws;
    short* wsb = (short*)d_ws;
    float* bm1f = (float*)(wsc + BM1F_BYTE);
    float* Zacc = (float*)(wsc + ACC_BYTE);
    float* macc = Zacc + ZACC_ELEMS;
    float* cnt  = macc + MACC_ELEMS;

    zero_kernel<<<2048, 256, 0, stream>>>(Zacc, ACC_TOTAL);
    fold_kernel<<<192, 256, 0, stream>>>(We, be, Wm1, bm1, wsb + WM1T_OFF, bm1f);
    prep_kernel<<<360, 256, 0, stream>>>(Wm2, Wv1, Wv2, Ws1, Ws2, wsb);
    edge_kernel<<<NED/EPB, 256, 0, stream>>>(Z, h, ei, edf, edv,
        wsb + WM1T_OFF, bm1f, wsb + WM2T_OFF, bm2, wsb + WV1T_OFF, bv1,
        wsb + WV2T_OFF, bv2, Zacc, macc, cnt);
    node_kernel<<<(NND + 63)/64, 256, 0, stream>>>(h, wsb + WS1T_OFF, bs1,
        wsb + WS2T_OFF, bs2, Zacc, macc, cnt, (float*)d_out);
}